// Round 4
// baseline (139.825 us; speedup 1.0000x reference)
//
#include <hip/hip_runtime.h>

// ---------------- problem constants ----------------
#define L_TOK   7680
#define NHEAD   16
#define HDIM    64
#define NBLK    60      // pooled tokens == 128-token blocks
#define KEEP    361     // 3600 - (3240-1) entries kept per head
// workspace layout (bytes)
#define QS_OFF   0u           // f64 [16][60][64]  = 491520
#define KS_OFF   491520u      // f64 [16][60][64]
#define CNT_OFF  983040u      // i32 [16*60]
#define COL_OFF  986880u      // i32 [16*60][60]
#define KHM_OFF  1217280u     // bf16 [16][60][128][64] swizzled = 15728640
#define VTM_OFF  16945920u    // bf16 [16][60][64][128] swizzled = 15728640
// probs f64 [16][3600] = 460800 B overlaid at KHM_OFF (dead before gather_kv runs)

typedef short bf16x8 __attribute__((ext_vector_type(8)));
typedef float f32x4  __attribute__((ext_vector_type(4)));

__device__ __forceinline__ unsigned short f2bf(float x) {
  unsigned int u = __float_as_uint(x);
  u += 0x7FFFu + ((u >> 16) & 1u);          // RNE
  return (unsigned short)(u >> 16);
}

// async global->LDS DMA, 16B per lane; lds base must be wave-uniform
__device__ __forceinline__ void gll16(const unsigned short* gsrc, unsigned short* ldst) {
  __builtin_amdgcn_global_load_lds(
      (const __attribute__((address_space(1))) unsigned int*)gsrc,
      (__attribute__((address_space(3))) unsigned int*)ldst, 16, 0, 0);
}

// ---------------- 1. pooling (f64 accumulate) ----------------
__global__ void pool_kernel(const float* __restrict__ qin, const float* __restrict__ kin,
                            double* __restrict__ qs, double* __restrict__ ks) {
  const int s = blockIdx.x, h = blockIdx.y, which = blockIdx.z, d = threadIdx.x;
  const float* in = which ? kin : qin;
  double* outp = which ? ks : qs;
  const int p = s / 5, c = s % 5;
  double acc = 0.0;
  for (int rr = 0; rr < 8; ++rr)
    for (int jj = 0; jj < 16; ++jj) {
      int tok = p * 640 + rr * 80 + c * 16 + jj;
      acc += (double)in[(size_t)tok * 1024 + h * 64 + d];
    }
  outp[(size_t)(h * 60 + s) * 64 + d] = acc * (1.0 / 128.0);
}

// ---------------- 2a. scores + row softmax (f64) ----------------
__global__ void scores_kernel(const double* __restrict__ qs, const double* __restrict__ ks,
                              double* __restrict__ probs) {
  const int i = blockIdx.x, h = blockIdx.y, j = threadIdx.x;   // 64 threads
  const double* qr = qs + (size_t)(h * 60 + i) * 64;
  double sc = -1.0e300;
  if (j < 60) {
    const double* kr = ks + (size_t)(h * 60 + j) * 64;
    double a0 = 0, a1 = 0, a2 = 0, a3 = 0;
    #pragma unroll
    for (int d = 0; d < 64; d += 4) {
      a0 += qr[d]     * kr[d];
      a1 += qr[d + 1] * kr[d + 1];
      a2 += qr[d + 2] * kr[d + 2];
      a3 += qr[d + 3] * kr[d + 3];
    }
    sc = ((a0 + a1) + (a2 + a3)) * 0.125;
  }
  double m = sc;
  #pragma unroll
  for (int o = 32; o; o >>= 1) m = fmax(m, __shfl_xor(m, o, 64));
  double e = (j < 60) ? exp(sc - m) : 0.0;
  double ssum = e;
  #pragma unroll
  for (int o = 32; o; o >>= 1) ssum += __shfl_xor(ssum, o, 64);
  if (j < 60) probs[(size_t)(h * 60 + i) * 60 + j] = e / ssum;
}

// ---------------- 2b. exact percentile via 6-pass radix select ----------------
__global__ __launch_bounds__(256) void select_kernel(const double* __restrict__ probs,
                                                     int* __restrict__ counts,
                                                     int* __restrict__ cols) {
  const int h = blockIdx.x, t = threadIdx.x;
  __shared__ double pb[3600];
  __shared__ int hist[2048];
  __shared__ int warr[4];
  __shared__ int sh_digit, sh_above;

  unsigned long long myv[15];
  #pragma unroll
  for (int m2 = 0; m2 < 15; ++m2) {          // static indexing (no scratch)
    int i = t + m2 * 256;
    double v = 0.0;
    if (i < 3600) { v = probs[(size_t)h * 3600 + i]; pb[i] = v; }
    myv[m2] = (unsigned long long)__double_as_longlong(v);  // 0 sentinel (probs > 0 always)
  }

  unsigned long long prefix = 0;
  int rank = KEEP;
  const int lane = t & 63, w = t >> 6;
  for (int pass = 0; pass < 6; ++pass) {
    const int shift = (pass < 5) ? (53 - 11 * pass) : 0;
    const int width = (pass < 5) ? 11 : 9;
    const int dmask = (1 << width) - 1;
    for (int i = t; i < 2048; i += 256) hist[i] = 0;
    __syncthreads();
    const int hb = shift + width;
    #pragma unroll
    for (int m2 = 0; m2 < 15; ++m2) {
      unsigned long long u = myv[m2];
      if (u && (pass == 0 || (u >> hb) == (prefix >> hb)))
        atomicAdd(&hist[(int)((u >> shift) & dmask)], 1);
    }
    __syncthreads();
    const int base = t * 8;
    int bcnt[8], s = 0;
    #pragma unroll
    for (int b = 0; b < 8; ++b) { bcnt[b] = hist[base + b]; s += bcnt[b]; }
    int incl = s;
    #pragma unroll
    for (int o = 1; o < 64; o <<= 1) {
      int y = __shfl_down(incl, o, 64);
      if (lane + o < 64) incl += y;
    }
    if (lane == 0) warr[w] = incl;
    __syncthreads();
    int above_w = 0;
    for (int w2 = w + 1; w2 < 4; ++w2) above_w += warr[w2];
    int run = (incl - s) + above_w;
    #pragma unroll
    for (int b = 7; b >= 0; --b) {
      int c = bcnt[b];
      if (c > 0 && run < rank && run + c >= rank) { sh_digit = base + b; sh_above = run; }
      run += c;
    }
    __syncthreads();
    prefix |= ((unsigned long long)sh_digit) << shift;
    rank -= sh_above;
    __syncthreads();
  }

  const double thr = __longlong_as_double((long long)prefix);
  if (t < 60) {
    int cnt = 0;
    for (int j = 0; j < 60; ++j)
      if (pb[t * 60 + j] >= thr) cols[(size_t)(h * 60 + t) * 60 + (cnt++)] = j;
    counts[h * 60 + t] = cnt;
  }
}

// ---------------- 3. gather K + V: reorg + bf16 + XOR swizzle into global -------
__global__ void gather_kv_kernel(const float* __restrict__ kin, const float* __restrict__ vin,
                                 unsigned short* __restrict__ khm, unsigned short* __restrict__ vtm) {
  __shared__ float vl[128 * 68];
  const int blk = blockIdx.x, h = blockIdx.y, t = threadIdx.x;
  const int p = blk / 5, c = blk % 5;
  // K part: khm[h][blk]: row*64 + (slot ^ (row&7))*8 + (d&7)
  unsigned short* kdst = khm + (size_t)(h * 60 + blk) * 8192;
  #pragma unroll
  for (int it = 0; it < 4; ++it) {
    int sidx = it * 256 + t;            // row(128) x slot(8)
    int row = sidx >> 3, s = sidx & 7;
    int tok = p * 640 + (row >> 4) * 80 + c * 16 + (row & 15);
    const float* src = kin + (size_t)tok * 1024 + h * 64 + s * 8;
    float4 a = ((const float4*)src)[0], b = ((const float4*)src)[1];
    union { uint4 u4; unsigned short us[8]; } un;
    un.us[0] = f2bf(a.x); un.us[1] = f2bf(a.y); un.us[2] = f2bf(a.z); un.us[3] = f2bf(a.w);
    un.us[4] = f2bf(b.x); un.us[5] = f2bf(b.y); un.us[6] = f2bf(b.z); un.us[7] = f2bf(b.w);
    *(uint4*)(kdst + row * 64 + ((s ^ (row & 7)) * 8)) = un.u4;
  }
  // V part: vtm[h][blk][d][key] transposed, swizzled
  #pragma unroll
  for (int it = 0; it < 8; ++it) {
    int idx = it * 256 + t;             // row(128) x float4(16)
    int row = idx >> 4, f4 = idx & 15;
    int tok = p * 640 + (row >> 4) * 80 + c * 16 + (row & 15);
    float4 a = ((const float4*)(vin + (size_t)tok * 1024 + h * 64))[f4];
    *(float4*)&vl[row * 68 + f4 * 4] = a;
  }
  __syncthreads();
  unsigned short* vdst = vtm + (size_t)(h * 60 + blk) * 8192;
  #pragma unroll
  for (int it = 0; it < 4; ++it) {
    int u = it * 256 + t;               // d(64) x slot(16)
    int d = u >> 4, s = u & 15;
    union { uint4 u4; unsigned short us[8]; } un;
    #pragma unroll
    for (int i = 0; i < 8; ++i) un.us[i] = f2bf(vl[(s * 8 + i) * 68 + d]);
    *(uint4*)(vdst + d * 128 + ((s ^ (d & 7)) * 8)) = un.u4;
  }
}

// ---------------- 4. block-sparse flash attention, bf16 MFMA ----------------
// grid (qb=60, h=16), 512 thr = 8 waves, wave w owns queries w*16..w*16+15
// LDS: K/V double-buffered (async gll DMA, counted vmcnt) + wave-private P half-tiles
__global__ __launch_bounds__(512, 4) void attn_kernel(
    const float* __restrict__ qin, const unsigned short* __restrict__ khm,
    const unsigned short* __restrict__ vtm, const int* __restrict__ counts,
    const int* __restrict__ cols, float* __restrict__ out) {
  const int qb = blockIdx.x, h = blockIdx.y;
  const int t = threadIdx.x, w = t >> 6, lane = t & 63;
  const int g = lane >> 4, n = lane & 15, sw = n & 7;
  __shared__ __align__(16) unsigned short Kt[2][8192];   // [buf][key 128][d 64] swizzled
  __shared__ __align__(16) unsigned short Vt[2][8192];   // [buf][d 64][key 128] swizzled
  __shared__ __align__(16) unsigned short Pt[8][1024];   // per-wave [16 q][64 k] swizzled

  const int cnt = counts[h * 60 + qb];
  const int pq = qb / 5, cq = qb % 5;
  if (cnt == 0) {   // fully-masked rows -> zero output
    for (int i = t; i < 2048; i += 512) {
      int row = i >> 4, f4 = i & 15;
      int tok = pq * 640 + (row >> 4) * 80 + cq * 16 + (row & 15);
      float4 z = {0.f, 0.f, 0.f, 0.f};
      *(float4*)(out + (size_t)tok * 1024 + h * 64 + f4 * 4) = z;
    }
    return;
  }

  // column list broadcast from lane registers (no per-iter global load)
  const int* mycols = cols + (size_t)(h * 60 + qb) * 60;
  int colv = mycols[lane < cnt ? lane : 0];

  // Q A-fragments straight to registers: rows w*16 + n
  bf16x8 aq[2];
  {
    int lq = w * 16 + n;
    int tok = pq * 640 + (lq >> 4) * 80 + cq * 16 + (lq & 15);
    const float* qrow = qin + (size_t)tok * 1024 + h * 64;
    #pragma unroll
    for (int hh = 0; hh < 2; ++hh) {
      const float4* s4 = (const float4*)(qrow + hh * 32 + g * 8);
      float4 a = s4[0], b2 = s4[1];
      union { bf16x8 v; unsigned short us[8]; } un;
      un.us[0] = f2bf(a.x); un.us[1] = f2bf(a.y); un.us[2] = f2bf(a.z); un.us[3] = f2bf(a.w);
      un.us[4] = f2bf(b2.x); un.us[5] = f2bf(b2.y); un.us[6] = f2bf(b2.z); un.us[7] = f2bf(b2.w);
      aq[hh] = un.v;
    }
  }

  const f32x4 zero4 = {0.f, 0.f, 0.f, 0.f};
  f32x4 acco[4];
  float mst[4], lst[4];
  #pragma unroll
  for (int dt = 0; dt < 4; ++dt) acco[dt] = zero4;
  #pragma unroll
  for (int r = 0; r < 4; ++r) { mst[r] = -1.0e38f; lst[r] = 0.f; }

  const unsigned short* khm_h = khm + (size_t)(h * 60) * 8192;
  const unsigned short* vtm_h = vtm + (size_t)(h * 60) * 8192;

  // prologue: DMA tile 0 into buf 0 (4 gll per thread: 2 K + 2 V)
  {
    int kb0 = __shfl(colv, 0, 64);
    asm volatile("s_waitcnt vmcnt(0)" ::: "memory");   // only gll in flight from here
    const unsigned short* ksrc = khm_h + (size_t)kb0 * 8192;
    const unsigned short* vsrc = vtm_h + (size_t)kb0 * 8192;
    #pragma unroll
    for (int r2 = 0; r2 < 2; ++r2) {
      gll16(ksrc + (size_t)(r2 * 512 + t) * 8, &Kt[0][r2 * 4096 + w * 512]);
      gll16(vsrc + (size_t)(r2 * 512 + t) * 8, &Vt[0][r2 * 4096 + w * 512]);
    }
  }

  for (int ki = 0; ki < cnt; ++ki) {
    const int b = ki & 1;
    __syncthreads();                          // all waves done reading buf b^1 (tile ki-1)
    if (ki + 1 < cnt) {                       // prefetch tile ki+1 into freed buf b^1
      int kbn = __shfl(colv, ki + 1, 64);
      const unsigned short* ksrc = khm_h + (size_t)kbn * 8192;
      const unsigned short* vsrc = vtm_h + (size_t)kbn * 8192;
      #pragma unroll
      for (int r2 = 0; r2 < 2; ++r2) {
        gll16(ksrc + (size_t)(r2 * 512 + t) * 8, &Kt[b ^ 1][r2 * 4096 + w * 512]);
        gll16(vsrc + (size_t)(r2 * 512 + t) * 8, &Vt[b ^ 1][r2 * 4096 + w * 512]);
      }
      asm volatile("s_waitcnt vmcnt(4)" ::: "memory");   // tile ki's 4 done; ki+1's in flight
    } else {
      asm volatile("s_waitcnt vmcnt(0)" ::: "memory");   // last tile: drain
    }
    __syncthreads();                          // tile ki ready for all waves

    // ---- QK^T: S[16q][128k] per wave ----
    f32x4 accs[8];
    #pragma unroll
    for (int kt = 0; kt < 8; ++kt) accs[kt] = zero4;
    #pragma unroll
    for (int kt = 0; kt < 8; ++kt) {
      int rowbase = (kt * 16 + n) * 64;
      bf16x8 b0 = *(const bf16x8*)&Kt[b][rowbase + ((g ^ sw) * 8)];
      bf16x8 b1 = *(const bf16x8*)&Kt[b][rowbase + (((4 + g) ^ sw) * 8)];
      accs[kt] = __builtin_amdgcn_mfma_f32_16x16x32_bf16(aq[0], b0, accs[kt], 0, 0, 0);
      accs[kt] = __builtin_amdgcn_mfma_f32_16x16x32_bf16(aq[1], b1, accs[kt], 0, 0, 0);
    }

    // ---- online softmax (row = 4g + r, col = kt*16 + n) ----
    float tm[4], mn[4], fs[4], rs[4];
    #pragma unroll
    for (int r = 0; r < 4; ++r) {
      float v = accs[0][r];
      #pragma unroll
      for (int kt = 1; kt < 8; ++kt) v = fmaxf(v, accs[kt][r]);
      tm[r] = v;
    }
    #pragma unroll
    for (int r = 0; r < 4; ++r) {
      #pragma unroll
      for (int msk = 1; msk < 16; msk <<= 1)
        tm[r] = fmaxf(tm[r], __shfl_xor(tm[r], msk, 64));
      mn[r] = fmaxf(mst[r], tm[r] * 0.125f);
      fs[r] = __expf(mst[r] - mn[r]);
      mst[r] = mn[r];
      rs[r] = 0.f;
    }
    #pragma unroll
    for (int dt = 0; dt < 4; ++dt)
      #pragma unroll
      for (int r = 0; r < 4; ++r) acco[dt][r] *= fs[r];
    #pragma unroll
    for (int kt = 0; kt < 8; ++kt)
      #pragma unroll
      for (int r = 0; r < 4; ++r) {
        float pv = __expf(accs[kt][r] * 0.125f - mn[r]);
        rs[r] += pv;
        accs[kt][r] = pv;
      }
    #pragma unroll
    for (int r = 0; r < 4; ++r) {
      #pragma unroll
      for (int msk = 1; msk < 16; msk <<= 1) rs[r] += __shfl_xor(rs[r], msk, 64);
      lst[r] = lst[r] * fs[r] + rs[r];
    }

    // ---- PV in two 64-key halves through wave-private P (no barriers) ----
    unsigned short* Pw = &Pt[w][0];
    #pragma unroll
    for (int hf = 0; hf < 2; ++hf) {
      #pragma unroll
      for (int kt2 = 0; kt2 < 4; ++kt2) {
        int slot = kt2 * 2 + (n >> 3);
        #pragma unroll
        for (int r = 0; r < 4; ++r) {
          int lqr = 4 * g + r;
          Pw[lqr * 64 + ((slot ^ (lqr & 7)) << 3) + (n & 7)] = f2bf(accs[hf * 4 + kt2][r]);
        }
      }
      asm volatile("s_waitcnt lgkmcnt(0)" ::: "memory");   // wave's P writes visible to itself
      #pragma unroll
      for (int ks = 0; ks < 2; ++ks) {
        bf16x8 pa = *(const bf16x8*)&Pw[n * 64 + (((ks * 4 + g) ^ sw) << 3)];
        #pragma unroll
        for (int dt = 0; dt < 4; ++dt) {
          int d = dt * 16 + n;
          bf16x8 vb = *(const bf16x8*)&Vt[b][d * 128 + ((((hf * 2 + ks) * 4 + g) ^ sw) << 3)];
          acco[dt] = __builtin_amdgcn_mfma_f32_16x16x32_bf16(pa, vb, acco[dt], 0, 0, 0);
        }
      }
    }
  }

  // ---- epilogue: O / l, scatter back through reorg ----
  #pragma unroll
  for (int r = 0; r < 4; ++r) {
    float inv = 1.0f / lst[r];
    int lq = w * 16 + 4 * g + r;
    int tok = pq * 640 + (lq >> 4) * 80 + cq * 16 + (lq & 15);
    float* op = out + (size_t)tok * 1024 + h * 64 + n;
    #pragma unroll
    for (int dt = 0; dt < 4; ++dt) op[dt * 16] = acco[dt][r] * inv;
  }
}

// ---------------- launch ----------------
extern "C" void kernel_launch(void* const* d_in, const int* in_sizes, int n_in,
                              void* d_out, int out_size, void* d_ws, size_t ws_size,
                              hipStream_t stream) {
  const float* qin = (const float*)d_in[0];
  const float* kin = (const float*)d_in[1];
  const float* vin = (const float*)d_in[2];
  char* ws = (char*)d_ws;
  double* qs = (double*)(ws + QS_OFF);
  double* ks = (double*)(ws + KS_OFF);
  int* counts = (int*)(ws + CNT_OFF);
  int* cols = (int*)(ws + COL_OFF);
  unsigned short* khm = (unsigned short*)(ws + KHM_OFF);
  unsigned short* vtm = (unsigned short*)(ws + VTM_OFF);
  double* probs = (double*)(ws + KHM_OFF);   // overlaid: dead before gather_kv writes khm
  float* outp = (float*)d_out;

  pool_kernel<<<dim3(60, 16, 2), 64, 0, stream>>>(qin, kin, qs, ks);
  scores_kernel<<<dim3(60, 16), 64, 0, stream>>>(qs, ks, probs);
  select_kernel<<<16, 256, 0, stream>>>(probs, counts, cols);
  gather_kv_kernel<<<dim3(60, 16), 256, 0, stream>>>(kin, vin, khm, vtm);
  attn_kernel<<<dim3(60, 16), 512, 0, stream>>>(qin, khm, vtm, counts, cols, outp);
}

// Round 5
// 131.719 us; speedup vs baseline: 1.0615x; 1.0615x over previous
//
#include <hip/hip_runtime.h>

// ---------------- problem constants ----------------
#define L_TOK   7680
#define NHEAD   16
#define HDIM    64
#define NBLK    60      // pooled tokens == 128-token blocks
#define KEEP    361     // 3600 - (3240-1) entries kept per head
// workspace layout (bytes)
#define QS_OFF   0u           // f64 [16][60][64]  = 491520
#define KS_OFF   491520u      // f64 [16][60][64]
#define CNT_OFF  983040u      // i32 [16*60]
#define COL_OFF  986880u      // i32 [16*60][60]
#define KHM_OFF  1217280u     // bf16 [16][60][128][64] swizzled = 15728640
#define VTM_OFF  16945920u    // bf16 [16][60][64][128] swizzled = 15728640
// probs f64 [16][3600] = 460800 B overlaid at KHM_OFF (dead before gather_kv runs)

typedef short bf16x8 __attribute__((ext_vector_type(8)));
typedef float f32x4  __attribute__((ext_vector_type(4)));

// hardware packed f32->bf16 RNE (1 inst for 2 elems). Pair order cancels
// between Q/K (d-pairs) and P/V (k-pairs), so lo/hi convention is non-critical.
__device__ __forceinline__ unsigned int cvtpk(float lo, float hi) {
  unsigned int r;
  asm("v_cvt_pk_bf16_f32 %0, %1, %2" : "=v"(r) : "v"(lo), "v"(hi));
  return r;
}

// async global->LDS DMA, 16B per lane; lds base must be wave-uniform
__device__ __forceinline__ void gll16(const unsigned short* gsrc, unsigned short* ldst) {
  __builtin_amdgcn_global_load_lds(
      (const __attribute__((address_space(1))) unsigned int*)gsrc,
      (__attribute__((address_space(3))) unsigned int*)ldst, 16, 0, 0);
}

// ---------------- 1. pooling (f64 accumulate) ----------------
__global__ void pool_kernel(const float* __restrict__ qin, const float* __restrict__ kin,
                            double* __restrict__ qs, double* __restrict__ ks) {
  const int s = blockIdx.x, h = blockIdx.y, which = blockIdx.z, d = threadIdx.x;
  const float* in = which ? kin : qin;
  double* outp = which ? ks : qs;
  const int p = s / 5, c = s % 5;
  double acc = 0.0;
  for (int rr = 0; rr < 8; ++rr)
    for (int jj = 0; jj < 16; ++jj) {
      int tok = p * 640 + rr * 80 + c * 16 + jj;
      acc += (double)in[(size_t)tok * 1024 + h * 64 + d];
    }
  outp[(size_t)(h * 60 + s) * 64 + d] = acc * (1.0 / 128.0);
}

// ---------------- 2a. scores + row softmax (f64) ----------------
__global__ void scores_kernel(const double* __restrict__ qs, const double* __restrict__ ks,
                              double* __restrict__ probs) {
  const int i = blockIdx.x, h = blockIdx.y, j = threadIdx.x;   // 64 threads
  const double* qr = qs + (size_t)(h * 60 + i) * 64;
  double sc = -1.0e300;
  if (j < 60) {
    const double* kr = ks + (size_t)(h * 60 + j) * 64;
    double a0 = 0, a1 = 0, a2 = 0, a3 = 0;
    #pragma unroll
    for (int d = 0; d < 64; d += 4) {
      a0 += qr[d]     * kr[d];
      a1 += qr[d + 1] * kr[d + 1];
      a2 += qr[d + 2] * kr[d + 2];
      a3 += qr[d + 3] * kr[d + 3];
    }
    sc = ((a0 + a1) + (a2 + a3)) * 0.125;
  }
  double m = sc;
  #pragma unroll
  for (int o = 32; o; o >>= 1) m = fmax(m, __shfl_xor(m, o, 64));
  double e = (j < 60) ? exp(sc - m) : 0.0;
  double ssum = e;
  #pragma unroll
  for (int o = 32; o; o >>= 1) ssum += __shfl_xor(ssum, o, 64);
  if (j < 60) probs[(size_t)(h * 60 + i) * 60 + j] = e / ssum;
}

// ---------------- 2b. exact percentile via 6-pass radix select ----------------
__global__ __launch_bounds__(256) void select_kernel(const double* __restrict__ probs,
                                                     int* __restrict__ counts,
                                                     int* __restrict__ cols) {
  const int h = blockIdx.x, t = threadIdx.x;
  __shared__ double pb[3600];
  __shared__ int hist[2048];
  __shared__ int warr[4];
  __shared__ int sh_digit, sh_above;

  unsigned long long myv[15];
  #pragma unroll
  for (int m2 = 0; m2 < 15; ++m2) {          // static indexing (no scratch)
    int i = t + m2 * 256;
    double v = 0.0;
    if (i < 3600) { v = probs[(size_t)h * 3600 + i]; pb[i] = v; }
    myv[m2] = (unsigned long long)__double_as_longlong(v);  // 0 sentinel (probs > 0 always)
  }

  unsigned long long prefix = 0;
  int rank = KEEP;
  const int lane = t & 63, w = t >> 6;
  for (int pass = 0; pass < 6; ++pass) {
    const int shift = (pass < 5) ? (53 - 11 * pass) : 0;
    const int width = (pass < 5) ? 11 : 9;
    const int dmask = (1 << width) - 1;
    for (int i = t; i < 2048; i += 256) hist[i] = 0;
    __syncthreads();
    const int hb = shift + width;
    #pragma unroll
    for (int m2 = 0; m2 < 15; ++m2) {
      unsigned long long u = myv[m2];
      if (u && (pass == 0 || (u >> hb) == (prefix >> hb)))
        atomicAdd(&hist[(int)((u >> shift) & dmask)], 1);
    }
    __syncthreads();
    const int base = t * 8;
    int bcnt[8], s = 0;
    #pragma unroll
    for (int b = 0; b < 8; ++b) { bcnt[b] = hist[base + b]; s += bcnt[b]; }
    int incl = s;
    #pragma unroll
    for (int o = 1; o < 64; o <<= 1) {
      int y = __shfl_down(incl, o, 64);
      if (lane + o < 64) incl += y;
    }
    if (lane == 0) warr[w] = incl;
    __syncthreads();
    int above_w = 0;
    for (int w2 = w + 1; w2 < 4; ++w2) above_w += warr[w2];
    int run = (incl - s) + above_w;
    #pragma unroll
    for (int b = 7; b >= 0; --b) {
      int c = bcnt[b];
      if (c > 0 && run < rank && run + c >= rank) { sh_digit = base + b; sh_above = run; }
      run += c;
    }
    __syncthreads();
    prefix |= ((unsigned long long)sh_digit) << shift;
    rank -= sh_above;
    __syncthreads();
  }

  const double thr = __longlong_as_double((long long)prefix);
  if (t < 60) {
    int cnt = 0;
    for (int j = 0; j < 60; ++j)
      if (pb[t * 60 + j] >= thr) cols[(size_t)(h * 60 + t) * 60 + (cnt++)] = j;
    counts[h * 60 + t] = cnt;
  }
}

// ---------------- 3. gather K + V: reorg + bf16 + XOR swizzle into global -------
__global__ void gather_kv_kernel(const float* __restrict__ kin, const float* __restrict__ vin,
                                 unsigned short* __restrict__ khm, unsigned short* __restrict__ vtm) {
  __shared__ float vl[128 * 68];
  const int blk = blockIdx.x, h = blockIdx.y, t = threadIdx.x;
  const int p = blk / 5, c = blk % 5;
  // K part: khm[h][blk]: row*64 + (slot ^ (row&7))*8 + (d&7)
  unsigned short* kdst = khm + (size_t)(h * 60 + blk) * 8192;
  #pragma unroll
  for (int it = 0; it < 4; ++it) {
    int sidx = it * 256 + t;            // row(128) x slot(8)
    int row = sidx >> 3, s = sidx & 7;
    int tok = p * 640 + (row >> 4) * 80 + c * 16 + (row & 15);
    const float* src = kin + (size_t)tok * 1024 + h * 64 + s * 8;
    float4 a = ((const float4*)src)[0], b = ((const float4*)src)[1];
    uint4 un;
    un.x = cvtpk(a.x, a.y); un.y = cvtpk(a.z, a.w);
    un.z = cvtpk(b.x, b.y); un.w = cvtpk(b.z, b.w);
    *(uint4*)(kdst + row * 64 + ((s ^ (row & 7)) * 8)) = un;
  }
  // V part: vtm[h][blk][d][key] transposed, swizzled
  #pragma unroll
  for (int it = 0; it < 8; ++it) {
    int idx = it * 256 + t;             // row(128) x float4(16)
    int row = idx >> 4, f4 = idx & 15;
    int tok = p * 640 + (row >> 4) * 80 + c * 16 + (row & 15);
    float4 a = ((const float4*)(vin + (size_t)tok * 1024 + h * 64))[f4];
    *(float4*)&vl[row * 68 + f4 * 4] = a;
  }
  __syncthreads();
  unsigned short* vdst = vtm + (size_t)(h * 60 + blk) * 8192;
  #pragma unroll
  for (int it = 0; it < 4; ++it) {
    int u = it * 256 + t;               // d(64) x slot(16)
    int d = u >> 4, s = u & 15;
    uint4 un;
    un.x = cvtpk(vl[(s * 8 + 0) * 68 + d], vl[(s * 8 + 1) * 68 + d]);
    un.y = cvtpk(vl[(s * 8 + 2) * 68 + d], vl[(s * 8 + 3) * 68 + d]);
    un.z = cvtpk(vl[(s * 8 + 4) * 68 + d], vl[(s * 8 + 5) * 68 + d]);
    un.w = cvtpk(vl[(s * 8 + 6) * 68 + d], vl[(s * 8 + 7) * 68 + d]);
    *(uint4*)(vdst + d * 128 + ((s ^ (d & 7)) * 8)) = un;
  }
}

// ---------------- 4. block-sparse flash attention, bf16 MFMA ----------------
// grid (qb=60, h=16), 512 thr = 8 waves, wave w owns queries w*16..w*16+15
// Swapped QK^T (S^T layout, q = lane n) -> softmax mostly in-lane, P stays in
// registers (cvt_pk + ds_bpermute redistribution). LDS = K/V dbuf only (64 KB).
__global__ __launch_bounds__(512, 4) void attn_kernel(
    const float* __restrict__ qin, const unsigned short* __restrict__ khm,
    const unsigned short* __restrict__ vtm, const int* __restrict__ counts,
    const int* __restrict__ cols, float* __restrict__ out) {
  const int qb = blockIdx.x, h = blockIdx.y;
  const int t = threadIdx.x, w = t >> 6, lane = t & 63;
  const int g = lane >> 4, n = lane & 15, sw = n & 7;
  __shared__ __align__(16) unsigned short Kt[2][8192];   // [buf][key 128][d 64] swizzled
  __shared__ __align__(16) unsigned short Vt[2][8192];   // [buf][d 64][key 128] swizzled

  const int cnt = counts[h * 60 + qb];
  const int pq = qb / 5, cq = qb % 5;
  if (cnt == 0) {   // fully-masked rows -> zero output
    for (int i = t; i < 2048; i += 512) {
      int row = i >> 4, f4 = i & 15;
      int tok = pq * 640 + (row >> 4) * 80 + cq * 16 + (row & 15);
      float4 z = {0.f, 0.f, 0.f, 0.f};
      *(float4*)(out + (size_t)tok * 1024 + h * 64 + f4 * 4) = z;
    }
    return;
  }

  // column list broadcast from lane registers
  const int* mycols = cols + (size_t)(h * 60 + qb) * 60;
  int colv = mycols[lane < cnt ? lane : 0];

  // Q B-fragments straight to registers: lane (g,n) holds Q[q=n][d=hh*32+8g..+7]
  bf16x8 aq[2];
  {
    int lq = w * 16 + n;
    int tok = pq * 640 + (lq >> 4) * 80 + cq * 16 + (lq & 15);
    const float* qrow = qin + (size_t)tok * 1024 + h * 64;
    #pragma unroll
    for (int hh = 0; hh < 2; ++hh) {
      const float4* s4 = (const float4*)(qrow + hh * 32 + g * 8);
      float4 a = s4[0], b2 = s4[1];
      union { bf16x8 v; unsigned int uw[4]; } un;
      un.uw[0] = cvtpk(a.x, a.y);  un.uw[1] = cvtpk(a.z, a.w);
      un.uw[2] = cvtpk(b2.x, b2.y); un.uw[3] = cvtpk(b2.z, b2.w);
      aq[hh] = un.v;
    }
  }

  const f32x4 zero4 = {0.f, 0.f, 0.f, 0.f};
  f32x4 acco[4];                       // O[q=4g+r][d=16dt+n]
  float mst = -1.0e38f, lst = 0.f;     // softmax state for q = n (base-2 domain)
  #pragma unroll
  for (int dt = 0; dt < 4; ++dt) acco[dt] = zero4;

  const unsigned short* khm_h = khm + (size_t)(h * 60) * 8192;
  const unsigned short* vtm_h = vtm + (size_t)(h * 60) * 8192;

  const int loSrc = ((g & 1) << 5) + n;    // lane of g' = 2*(g&1)
  const int hiSrc = loSrc + 16;            // lane of g' = 2*(g&1)+1
  const bool glo = (g < 2);
  const int rowlane = (g << 4) + (g << 2); // +r -> a lane holding state for q=4g+r
  const float C2 = 0.18033688011112042f;   // 0.125 * log2(e)

  // prologue: DMA tile 0 into buf 0 (4 gll per thread: 2 K + 2 V)
  {
    int kb0 = __shfl(colv, 0, 64);
    asm volatile("s_waitcnt vmcnt(0)" ::: "memory");   // only gll in flight from here
    const unsigned short* ksrc = khm_h + (size_t)kb0 * 8192;
    const unsigned short* vsrc = vtm_h + (size_t)kb0 * 8192;
    #pragma unroll
    for (int r2 = 0; r2 < 2; ++r2) {
      gll16(ksrc + (size_t)(r2 * 512 + t) * 8, &Kt[0][r2 * 4096 + w * 512]);
      gll16(vsrc + (size_t)(r2 * 512 + t) * 8, &Vt[0][r2 * 4096 + w * 512]);
    }
  }

  for (int ki = 0; ki < cnt; ++ki) {
    const int b = ki & 1;
    __syncthreads();                          // all waves done reading buf b^1
    if (ki + 1 < cnt) {                       // prefetch tile ki+1 into freed buf b^1
      int kbn = __shfl(colv, ki + 1, 64);
      const unsigned short* ksrc = khm_h + (size_t)kbn * 8192;
      const unsigned short* vsrc = vtm_h + (size_t)kbn * 8192;
      #pragma unroll
      for (int r2 = 0; r2 < 2; ++r2) {
        gll16(ksrc + (size_t)(r2 * 512 + t) * 8, &Kt[b ^ 1][r2 * 4096 + w * 512]);
        gll16(vsrc + (size_t)(r2 * 512 + t) * 8, &Vt[b ^ 1][r2 * 4096 + w * 512]);
      }
      asm volatile("s_waitcnt vmcnt(4)" ::: "memory");   // tile ki done; ki+1 in flight
    } else {
      asm volatile("s_waitcnt vmcnt(0)" ::: "memory");
    }
    __syncthreads();                          // tile ki ready for all waves

    // ---- swapped QK^T: St[k][q], lane (g,n) reg r of accs[kt]: k=16kt+4g+r, q=n
    f32x4 accs[8];
    #pragma unroll
    for (int kt = 0; kt < 8; ++kt) accs[kt] = zero4;
    __builtin_amdgcn_s_setprio(1);
    #pragma unroll
    for (int kt = 0; kt < 8; ++kt) {
      int rowbase = (kt * 16 + n) * 64;
      bf16x8 k0 = *(const bf16x8*)&Kt[b][rowbase + ((g ^ sw) * 8)];
      bf16x8 k1 = *(const bf16x8*)&Kt[b][rowbase + (((4 + g) ^ sw) * 8)];
      accs[kt] = __builtin_amdgcn_mfma_f32_16x16x32_bf16(k0, aq[0], accs[kt], 0, 0, 0);
      accs[kt] = __builtin_amdgcn_mfma_f32_16x16x32_bf16(k1, aq[1], accs[kt], 0, 0, 0);
    }
    __builtin_amdgcn_s_setprio(0);

    // ---- online softmax for q=n: in-lane over 32 k, butterfly over 4-lane group
    float mloc = -1.0e38f;
    #pragma unroll
    for (int kt = 0; kt < 8; ++kt) {
      float m01 = fmaxf(fmaxf(accs[kt][0], accs[kt][1]), fmaxf(accs[kt][2], accs[kt][3]));
      mloc = fmaxf(mloc, m01);
    }
    mloc = fmaxf(mloc, __shfl_xor(mloc, 16, 64));
    mloc = fmaxf(mloc, __shfl_xor(mloc, 32, 64));
    float mn = fmaxf(mst, mloc * C2);
    float fsq = __builtin_amdgcn_exp2f(mst - mn);
    mst = mn;
    float rs0 = 0.f, rs1 = 0.f, rs2 = 0.f, rs3 = 0.f;
    #pragma unroll
    for (int kt = 0; kt < 8; ++kt) {
      float p0 = __builtin_amdgcn_exp2f(fmaf(accs[kt][0], C2, -mn));
      float p1 = __builtin_amdgcn_exp2f(fmaf(accs[kt][1], C2, -mn));
      float p2 = __builtin_amdgcn_exp2f(fmaf(accs[kt][2], C2, -mn));
      float p3 = __builtin_amdgcn_exp2f(fmaf(accs[kt][3], C2, -mn));
      accs[kt][0] = p0; accs[kt][1] = p1; accs[kt][2] = p2; accs[kt][3] = p3;
      rs0 += p0; rs1 += p1; rs2 += p2; rs3 += p3;
    }
    float rsum = (rs0 + rs1) + (rs2 + rs3);
    rsum += __shfl_xor(rsum, 16, 64);
    rsum += __shfl_xor(rsum, 32, 64);
    lst = lst * fsq + rsum;

    // rescale O: need fs for q=4g+r (lives at lanes with n'=4g+r)
    float fso[4];
    #pragma unroll
    for (int r = 0; r < 4; ++r) fso[r] = __shfl(fsq, rowlane + r, 64);
    #pragma unroll
    for (int dt = 0; dt < 4; ++dt)
      #pragma unroll
      for (int r = 0; r < 4; ++r) acco[dt][r] *= fso[r];

    // ---- pack P to bf16 pairs (k-pairs): pku[kt][p] = {P[k=16kt+4g+2p], P[..+1]}
    unsigned int pku[8][2];
    #pragma unroll
    for (int kt = 0; kt < 8; ++kt) {
      pku[kt][0] = cvtpk(accs[kt][0], accs[kt][1]);
      pku[kt][1] = cvtpk(accs[kt][2], accs[kt][3]);
    }

    // ---- PV per 32-k slice: redistribute P to A-frag via bpermute, then mfma
    #pragma unroll
    for (int s = 0; s < 4; ++s) {
      union { unsigned int uw[4]; bf16x8 v; } pw;
      {
        unsigned int a0 = __shfl(pku[2 * s][0],     loSrc, 64);
        unsigned int b0 = __shfl(pku[2 * s + 1][0], loSrc, 64);
        pw.uw[0] = glo ? a0 : b0;
        unsigned int a1 = __shfl(pku[2 * s][1],     loSrc, 64);
        unsigned int b1 = __shfl(pku[2 * s + 1][1], loSrc, 64);
        pw.uw[1] = glo ? a1 : b1;
        unsigned int a2 = __shfl(pku[2 * s][0],     hiSrc, 64);
        unsigned int b2 = __shfl(pku[2 * s + 1][0], hiSrc, 64);
        pw.uw[2] = glo ? a2 : b2;
        unsigned int a3 = __shfl(pku[2 * s][1],     hiSrc, 64);
        unsigned int b3 = __shfl(pku[2 * s + 1][1], hiSrc, 64);
        pw.uw[3] = glo ? a3 : b3;
      }
      __builtin_amdgcn_s_setprio(1);
      #pragma unroll
      for (int dt = 0; dt < 4; ++dt) {
        int d = dt * 16 + n;
        bf16x8 vb = *(const bf16x8*)&Vt[b][d * 128 + (((s * 4 + g) ^ sw) * 8)];
        acco[dt] = __builtin_amdgcn_mfma_f32_16x16x32_bf16(pw.v, vb, acco[dt], 0, 0, 0);
      }
      __builtin_amdgcn_s_setprio(0);
    }
  }

  // ---- epilogue: O / l (l lives at lanes n'=4g+r), scatter through reorg ----
  float lv[4];
  #pragma unroll
  for (int r = 0; r < 4; ++r) lv[r] = __shfl(lst, rowlane + r, 64);
  #pragma unroll
  for (int r = 0; r < 4; ++r) {
    float inv = 1.0f / lv[r];
    int lq = w * 16 + 4 * g + r;
    int tok = pq * 640 + (lq >> 4) * 80 + cq * 16 + (lq & 15);
    float* op = out + (size_t)tok * 1024 + h * 64 + n;
    #pragma unroll
    for (int dt = 0; dt < 4; ++dt) op[dt * 16] = acco[dt][r] * inv;
  }
}

// ---------------- launch ----------------
extern "C" void kernel_launch(void* const* d_in, const int* in_sizes, int n_in,
                              void* d_out, int out_size, void* d_ws, size_t ws_size,
                              hipStream_t stream) {
  const float* qin = (const float*)d_in[0];
  const float* kin = (const float*)d_in[1];
  const float* vin = (const float*)d_in[2];
  char* ws = (char*)d_ws;
  double* qs = (double*)(ws + QS_OFF);
  double* ks = (double*)(ws + KS_OFF);
  int* counts = (int*)(ws + CNT_OFF);
  int* cols = (int*)(ws + COL_OFF);
  unsigned short* khm = (unsigned short*)(ws + KHM_OFF);
  unsigned short* vtm = (unsigned short*)(ws + VTM_OFF);
  double* probs = (double*)(ws + KHM_OFF);   // overlaid: dead before gather_kv writes khm
  float* outp = (float*)d_out;

  pool_kernel<<<dim3(60, 16, 2), 64, 0, stream>>>(qin, kin, qs, ks);
  scores_kernel<<<dim3(60, 16), 64, 0, stream>>>(qs, ks, probs);
  select_kernel<<<16, 256, 0, stream>>>(probs, counts, cols);
  gather_kv_kernel<<<dim3(60, 16), 256, 0, stream>>>(kin, vin, khm, vtm);
  attn_kernel<<<dim3(60, 16), 512, 0, stream>>>(qin, khm, vtm, counts, cols, outp);
}

// Round 6
// 120.038 us; speedup vs baseline: 1.1648x; 1.0973x over previous
//
#include <hip/hip_runtime.h>

// ---------------- problem constants ----------------
#define L_TOK   7680
#define NHEAD   16
#define HDIM    64
#define NBLK    60      // pooled tokens == 128-token blocks
#define KEEP    361     // 3600 - (3240-1) entries kept per head
// workspace layout (bytes)
#define QS_OFF   0u           // f64 [16][60][64]  = 491520
#define KS_OFF   491520u      // f64 [16][60][64]
#define CNT_OFF  983040u      // i32 [16*60]
#define COL_OFF  986880u      // i32 [16*60][60]
#define KHM_OFF  1217280u     // bf16 [16][60][128][64] swizzled = 15728640
#define VTM_OFF  16945920u    // bf16 [16][60][64][128] swizzled = 15728640
// probs f64 [16][3600] = 460800 B overlaid at KHM_OFF (dead before gather_kv runs)

typedef short bf16x8 __attribute__((ext_vector_type(8)));
typedef short bf16x4 __attribute__((ext_vector_type(4)));
typedef float f32x4  __attribute__((ext_vector_type(4)));

// hardware packed f32->bf16 RNE (1 inst for 2 elems)
__device__ __forceinline__ unsigned int cvtpk(float lo, float hi) {
  unsigned int r;
  asm("v_cvt_pk_bf16_f32 %0, %1, %2" : "=v"(r) : "v"(lo), "v"(hi));
  return r;
}

// 16x16x16 bf16 MFMA (K=16): B-frag rows k=4g+j match C/D row groups 4g+r,
// so packed cvt_pk pairs feed B directly (no cross-lane redistribution).
__device__ __forceinline__ f32x4 mfma16(bf16x4 a, bf16x4 b, f32x4 c) {
#if __has_builtin(__builtin_amdgcn_mfma_f32_16x16x16bf16_1k)
  return __builtin_amdgcn_mfma_f32_16x16x16bf16_1k(a, b, c, 0, 0, 0);
#else
  asm("v_mfma_f32_16x16x16_bf16 %0, %1, %2, %0" : "+v"(c) : "v"(a), "v"(b));
  return c;
#endif
}

// async global->LDS DMA, 16B per lane; lds base must be wave-uniform
__device__ __forceinline__ void gll16(const unsigned short* gsrc, unsigned short* ldst) {
  __builtin_amdgcn_global_load_lds(
      (const __attribute__((address_space(1))) unsigned int*)gsrc,
      (__attribute__((address_space(3))) unsigned int*)ldst, 16, 0, 0);
}

// ---------------- 1. pooling (f64 accumulate) ----------------
__global__ void pool_kernel(const float* __restrict__ qin, const float* __restrict__ kin,
                            double* __restrict__ qs, double* __restrict__ ks) {
  const int s = blockIdx.x, h = blockIdx.y, which = blockIdx.z, d = threadIdx.x;
  const float* in = which ? kin : qin;
  double* outp = which ? ks : qs;
  const int p = s / 5, c = s % 5;
  double acc = 0.0;
  for (int rr = 0; rr < 8; ++rr)
    for (int jj = 0; jj < 16; ++jj) {
      int tok = p * 640 + rr * 80 + c * 16 + jj;
      acc += (double)in[(size_t)tok * 1024 + h * 64 + d];
    }
  outp[(size_t)(h * 60 + s) * 64 + d] = acc * (1.0 / 128.0);
}

// ---------------- 2a. scores + row softmax (f64) ----------------
__global__ void scores_kernel(const double* __restrict__ qs, const double* __restrict__ ks,
                              double* __restrict__ probs) {
  const int i = blockIdx.x, h = blockIdx.y, j = threadIdx.x;   // 64 threads
  const double* qr = qs + (size_t)(h * 60 + i) * 64;
  double sc = -1.0e300;
  if (j < 60) {
    const double* kr = ks + (size_t)(h * 60 + j) * 64;
    double a0 = 0, a1 = 0, a2 = 0, a3 = 0;
    #pragma unroll
    for (int d = 0; d < 64; d += 4) {
      a0 += qr[d]     * kr[d];
      a1 += qr[d + 1] * kr[d + 1];
      a2 += qr[d + 2] * kr[d + 2];
      a3 += qr[d + 3] * kr[d + 3];
    }
    sc = ((a0 + a1) + (a2 + a3)) * 0.125;
  }
  double m = sc;
  #pragma unroll
  for (int o = 32; o; o >>= 1) m = fmax(m, __shfl_xor(m, o, 64));
  double e = (j < 60) ? exp(sc - m) : 0.0;
  double ssum = e;
  #pragma unroll
  for (int o = 32; o; o >>= 1) ssum += __shfl_xor(ssum, o, 64);
  if (j < 60) probs[(size_t)(h * 60 + i) * 60 + j] = e / ssum;
}

// ---------------- 2b. exact percentile via 6-pass radix select ----------------
__global__ __launch_bounds__(256) void select_kernel(const double* __restrict__ probs,
                                                     int* __restrict__ counts,
                                                     int* __restrict__ cols) {
  const int h = blockIdx.x, t = threadIdx.x;
  __shared__ double pb[3600];
  __shared__ int hist[2048];
  __shared__ int warr[4];
  __shared__ int sh_digit, sh_above;

  unsigned long long myv[15];
  #pragma unroll
  for (int m2 = 0; m2 < 15; ++m2) {          // static indexing (no scratch)
    int i = t + m2 * 256;
    double v = 0.0;
    if (i < 3600) { v = probs[(size_t)h * 3600 + i]; pb[i] = v; }
    myv[m2] = (unsigned long long)__double_as_longlong(v);  // 0 sentinel (probs > 0 always)
  }

  unsigned long long prefix = 0;
  int rank = KEEP;
  const int lane = t & 63, w = t >> 6;
  for (int pass = 0; pass < 6; ++pass) {
    const int shift = (pass < 5) ? (53 - 11 * pass) : 0;
    const int width = (pass < 5) ? 11 : 9;
    const int dmask = (1 << width) - 1;
    for (int i = t; i < 2048; i += 256) hist[i] = 0;
    __syncthreads();
    const int hb = shift + width;
    #pragma unroll
    for (int m2 = 0; m2 < 15; ++m2) {
      unsigned long long u = myv[m2];
      if (u && (pass == 0 || (u >> hb) == (prefix >> hb)))
        atomicAdd(&hist[(int)((u >> shift) & dmask)], 1);
    }
    __syncthreads();
    const int base = t * 8;
    int bcnt[8], s = 0;
    #pragma unroll
    for (int b = 0; b < 8; ++b) { bcnt[b] = hist[base + b]; s += bcnt[b]; }
    int incl = s;
    #pragma unroll
    for (int o = 1; o < 64; o <<= 1) {
      int y = __shfl_down(incl, o, 64);
      if (lane + o < 64) incl += y;
    }
    if (lane == 0) warr[w] = incl;
    __syncthreads();
    int above_w = 0;
    for (int w2 = w + 1; w2 < 4; ++w2) above_w += warr[w2];
    int run = (incl - s) + above_w;
    #pragma unroll
    for (int b = 7; b >= 0; --b) {
      int c = bcnt[b];
      if (c > 0 && run < rank && run + c >= rank) { sh_digit = base + b; sh_above = run; }
      run += c;
    }
    __syncthreads();
    prefix |= ((unsigned long long)sh_digit) << shift;
    rank -= sh_above;
    __syncthreads();
  }

  const double thr = __longlong_as_double((long long)prefix);
  if (t < 60) {
    int cnt = 0;
    for (int j = 0; j < 60; ++j)
      if (pb[t * 60 + j] >= thr) cols[(size_t)(h * 60 + t) * 60 + (cnt++)] = j;
    counts[h * 60 + t] = cnt;
  }
}

// ---------------- 3. gather K + V: reorg + bf16 + XOR swizzle into global -------
__global__ void gather_kv_kernel(const float* __restrict__ kin, const float* __restrict__ vin,
                                 unsigned short* __restrict__ khm, unsigned short* __restrict__ vtm) {
  __shared__ float vl[128 * 68];
  const int blk = blockIdx.x, h = blockIdx.y, t = threadIdx.x;
  const int p = blk / 5, c = blk % 5;
  // K part: khm[h][blk]: row*64 + (slot ^ (row&7))*8 + (d&7)
  unsigned short* kdst = khm + (size_t)(h * 60 + blk) * 8192;
  #pragma unroll
  for (int it = 0; it < 4; ++it) {
    int sidx = it * 256 + t;            // row(128) x slot(8)
    int row = sidx >> 3, s = sidx & 7;
    int tok = p * 640 + (row >> 4) * 80 + c * 16 + (row & 15);
    const float* src = kin + (size_t)tok * 1024 + h * 64 + s * 8;
    float4 a = ((const float4*)src)[0], b = ((const float4*)src)[1];
    uint4 un;
    un.x = cvtpk(a.x, a.y); un.y = cvtpk(a.z, a.w);
    un.z = cvtpk(b.x, b.y); un.w = cvtpk(b.z, b.w);
    *(uint4*)(kdst + row * 64 + ((s ^ (row & 7)) * 8)) = un;
  }
  // V part: vtm[h][blk][d][key] transposed, swizzled
  #pragma unroll
  for (int it = 0; it < 8; ++it) {
    int idx = it * 256 + t;             // row(128) x float4(16)
    int row = idx >> 4, f4 = idx & 15;
    int tok = p * 640 + (row >> 4) * 80 + c * 16 + (row & 15);
    float4 a = ((const float4*)(vin + (size_t)tok * 1024 + h * 64))[f4];
    *(float4*)&vl[row * 68 + f4 * 4] = a;
  }
  __syncthreads();
  unsigned short* vdst = vtm + (size_t)(h * 60 + blk) * 8192;
  #pragma unroll
  for (int it = 0; it < 4; ++it) {
    int u = it * 256 + t;               // d(64) x slot(16)
    int d = u >> 4, s = u & 15;
    uint4 un;
    un.x = cvtpk(vl[(s * 8 + 0) * 68 + d], vl[(s * 8 + 1) * 68 + d]);
    un.y = cvtpk(vl[(s * 8 + 2) * 68 + d], vl[(s * 8 + 3) * 68 + d]);
    un.z = cvtpk(vl[(s * 8 + 4) * 68 + d], vl[(s * 8 + 5) * 68 + d]);
    un.w = cvtpk(vl[(s * 8 + 6) * 68 + d], vl[(s * 8 + 7) * 68 + d]);
    *(uint4*)(vdst + d * 128 + ((s ^ (d & 7)) * 8)) = un;
  }
}

// ---------------- 4. block-sparse flash attention, bf16 MFMA ----------------
// grid (qb=60, h=16), 512 thr = 8 waves, wave w owns queries w*16..w*16+15
// Swapped QK^T (S^T, q=lane n) -> in-lane softmax; PV via 16x16x16 MFMA with
// B = packed P^T pairs (zero redistribution) producing O^T; O transposed via
// LDS once at epilogue. LDS = K/V dbuf 64 KB, aliased by Ot[128][68] at end.
__global__ __launch_bounds__(512, 4) void attn_kernel(
    const float* __restrict__ qin, const unsigned short* __restrict__ khm,
    const unsigned short* __restrict__ vtm, const int* __restrict__ counts,
    const int* __restrict__ cols, float* __restrict__ out) {
  const int qb = blockIdx.x, h = blockIdx.y;
  const int t = threadIdx.x, w = t >> 6, lane = t & 63;
  const int g = lane >> 4, n = lane & 15, sw = n & 7;
  __shared__ __align__(16) unsigned short LDSb[32768];   // 64 KB
  // Kt[b] at LDSb + b*8192 : [key 128][d 64] swizzled
  // Vt[b] at LDSb + 16384 + b*8192 : [d 64][key 128] swizzled
  #define KT(b) (LDSb + (b) * 8192)
  #define VT(b) (LDSb + 16384 + (b) * 8192)

  const int cnt = counts[h * 60 + qb];
  const int pq = qb / 5, cq = qb % 5;
  if (cnt == 0) {   // fully-masked rows -> zero output
    for (int i = t; i < 2048; i += 512) {
      int row = i >> 4, f4 = i & 15;
      int tok = pq * 640 + (row >> 4) * 80 + cq * 16 + (row & 15);
      float4 z = {0.f, 0.f, 0.f, 0.f};
      *(float4*)(out + (size_t)tok * 1024 + h * 64 + f4 * 4) = z;
    }
    return;
  }

  // column list broadcast from lane registers
  const int* mycols = cols + (size_t)(h * 60 + qb) * 60;
  int colv = mycols[lane < cnt ? lane : 0];

  // Q B-fragments straight to registers: lane (g,n) holds Q[q=n][d=hh*32+8g..+7]
  bf16x8 aq[2];
  {
    int lq = w * 16 + n;
    int tok = pq * 640 + (lq >> 4) * 80 + cq * 16 + (lq & 15);
    const float* qrow = qin + (size_t)tok * 1024 + h * 64;
    #pragma unroll
    for (int hh = 0; hh < 2; ++hh) {
      const float4* s4 = (const float4*)(qrow + hh * 32 + g * 8);
      float4 a = s4[0], b2 = s4[1];
      union { bf16x8 v; unsigned int uw[4]; } un;
      un.uw[0] = cvtpk(a.x, a.y);  un.uw[1] = cvtpk(a.z, a.w);
      un.uw[2] = cvtpk(b2.x, b2.y); un.uw[3] = cvtpk(b2.z, b2.w);
      aq[hh] = un.v;
    }
  }

  const f32x4 zero4 = {0.f, 0.f, 0.f, 0.f};
  f32x4 acco[4];                       // O^T: lane (g,n) holds O[q=n][d=16dt+4g+r]
  float mst = -1.0e38f, lst = 0.f;     // softmax state for q = n (base-2 domain)
  #pragma unroll
  for (int dt = 0; dt < 4; ++dt) acco[dt] = zero4;

  const unsigned short* khm_h = khm + (size_t)(h * 60) * 8192;
  const unsigned short* vtm_h = vtm + (size_t)(h * 60) * 8192;
  const float C2 = 0.18033688011112042f;   // 0.125 * log2(e)

  // prologue: DMA tile 0 into buf 0 (4 gll insts: 2 K + 2 V)
  {
    int kb0 = __shfl(colv, 0, 64);
    asm volatile("s_waitcnt vmcnt(0)" ::: "memory");   // only gll in flight from here
    const unsigned short* ksrc = khm_h + (size_t)kb0 * 8192;
    const unsigned short* vsrc = vtm_h + (size_t)kb0 * 8192;
    #pragma unroll
    for (int r2 = 0; r2 < 2; ++r2) {
      gll16(ksrc + (size_t)(r2 * 512 + t) * 8, KT(0) + r2 * 4096 + w * 512);
      gll16(vsrc + (size_t)(r2 * 512 + t) * 8, VT(0) + r2 * 4096 + w * 512);
    }
  }

  for (int ki = 0; ki < cnt; ++ki) {
    const int b = ki & 1;
    __syncthreads();                          // all waves done reading buf b^1
    if (ki + 1 < cnt) {                       // prefetch tile ki+1 into freed buf b^1
      int kbn = __shfl(colv, ki + 1, 64);
      const unsigned short* ksrc = khm_h + (size_t)kbn * 8192;
      const unsigned short* vsrc = vtm_h + (size_t)kbn * 8192;
      #pragma unroll
      for (int r2 = 0; r2 < 2; ++r2) {
        gll16(ksrc + (size_t)(r2 * 512 + t) * 8, KT(b ^ 1) + r2 * 4096 + w * 512);
        gll16(vsrc + (size_t)(r2 * 512 + t) * 8, VT(b ^ 1) + r2 * 4096 + w * 512);
      }
      asm volatile("s_waitcnt vmcnt(4)" ::: "memory");   // tile ki done; ki+1 in flight
    } else {
      asm volatile("s_waitcnt vmcnt(0)" ::: "memory");
    }
    __syncthreads();                          // tile ki ready for all waves

    // ---- swapped QK^T: St[k][q], lane (g,n) reg r of accs[kt]: k=16kt+4g+r, q=n
    f32x4 accs[8];
    #pragma unroll
    for (int kt = 0; kt < 8; ++kt) accs[kt] = zero4;
    __builtin_amdgcn_s_setprio(1);
    #pragma unroll
    for (int kt = 0; kt < 8; ++kt) {
      int rowbase = (kt * 16 + n) * 64;
      bf16x8 k0 = *(const bf16x8*)&KT(b)[rowbase + ((g ^ sw) * 8)];
      bf16x8 k1 = *(const bf16x8*)&KT(b)[rowbase + (((4 + g) ^ sw) * 8)];
      accs[kt] = __builtin_amdgcn_mfma_f32_16x16x32_bf16(k0, aq[0], accs[kt], 0, 0, 0);
      accs[kt] = __builtin_amdgcn_mfma_f32_16x16x32_bf16(k1, aq[1], accs[kt], 0, 0, 0);
    }
    __builtin_amdgcn_s_setprio(0);

    // ---- online softmax for q=n: in-lane over 32 k, butterfly over 4-lane group
    float mloc = -1.0e38f;
    #pragma unroll
    for (int kt = 0; kt < 8; ++kt) {
      float m01 = fmaxf(fmaxf(accs[kt][0], accs[kt][1]), fmaxf(accs[kt][2], accs[kt][3]));
      mloc = fmaxf(mloc, m01);
    }
    mloc = fmaxf(mloc, __shfl_xor(mloc, 16, 64));
    mloc = fmaxf(mloc, __shfl_xor(mloc, 32, 64));
    float mn = fmaxf(mst, mloc * C2);
    float fsq = __builtin_amdgcn_exp2f(mst - mn);
    mst = mn;
    float rs0 = 0.f, rs1 = 0.f, rs2 = 0.f, rs3 = 0.f;
    #pragma unroll
    for (int kt = 0; kt < 8; ++kt) {
      float p0 = __builtin_amdgcn_exp2f(fmaf(accs[kt][0], C2, -mn));
      float p1 = __builtin_amdgcn_exp2f(fmaf(accs[kt][1], C2, -mn));
      float p2 = __builtin_amdgcn_exp2f(fmaf(accs[kt][2], C2, -mn));
      float p3 = __builtin_amdgcn_exp2f(fmaf(accs[kt][3], C2, -mn));
      accs[kt][0] = p0; accs[kt][1] = p1; accs[kt][2] = p2; accs[kt][3] = p3;
      rs0 += p0; rs1 += p1; rs2 += p2; rs3 += p3;
    }
    float rsum = (rs0 + rs1) + (rs2 + rs3);
    rsum += __shfl_xor(rsum, 16, 64);
    rsum += __shfl_xor(rsum, 32, 64);
    lst = lst * fsq + rsum;

    // rescale O^T (q = n, in-lane -- no shuffles)
    #pragma unroll
    for (int dt = 0; dt < 4; ++dt)
      #pragma unroll
      for (int r = 0; r < 4; ++r) acco[dt][r] *= fsq;

    // ---- pack P^T to bf16 B-frags: pb[kt] = {P[k=16kt+4g+0..3][q=n]} ----
    bf16x4 pbv[8];
    #pragma unroll
    for (int kt = 0; kt < 8; ++kt) {
      union { unsigned int u[2]; bf16x4 v; } pb;
      pb.u[0] = cvtpk(accs[kt][0], accs[kt][1]);
      pb.u[1] = cvtpk(accs[kt][2], accs[kt][3]);
      pbv[kt] = pb.v;
    }

    // ---- PV via 16x16x16: A = V^T[d=16dt+n][k=16kt+4g+0..3] (b64, swizzled) ----
    __builtin_amdgcn_s_setprio(1);
    #pragma unroll
    for (int kt = 0; kt < 8; ++kt) {
      #pragma unroll
      for (int dt = 0; dt < 4; ++dt) {
        int d = dt * 16 + n;
        bf16x4 va = *(const bf16x4*)&VT(b)[d * 128 + (((2 * kt + (g >> 1)) ^ sw) * 8) + (g & 1) * 4];
        acco[dt] = mfma16(va, pbv[kt], acco[dt]);
      }
    }
    __builtin_amdgcn_s_setprio(0);
  }

  // ---- epilogue: O^T / l -> LDS transpose -> coalesced float4 stores ----
  __syncthreads();                         // all waves done with K/V LDS
  float* Ot = (float*)LDSb;                // [128][68] padded
  {
    float inv = 1.0f / lst;
    int q = w * 16 + n;
    #pragma unroll
    for (int dt = 0; dt < 4; ++dt)
      #pragma unroll
      for (int r = 0; r < 4; ++r)
        Ot[q * 68 + dt * 16 + 4 * g + r] = acco[dt][r] * inv;
  }
  __syncthreads();
  for (int i = t; i < 2048; i += 512) {
    int q = i >> 4, f4 = i & 15;
    int tok = pq * 640 + (q >> 4) * 80 + cq * 16 + (q & 15);
    float4 val = *(float4*)&Ot[q * 68 + f4 * 4];
    *(float4*)(out + (size_t)tok * 1024 + h * 64 + f4 * 4) = val;
  }
  #undef KT
  #undef VT
}

// ---------------- launch ----------------
extern "C" void kernel_launch(void* const* d_in, const int* in_sizes, int n_in,
                              void* d_out, int out_size, void* d_ws, size_t ws_size,
                              hipStream_t stream) {
  const float* qin = (const float*)d_in[0];
  const float* kin = (const float*)d_in[1];
  const float* vin = (const float*)d_in[2];
  char* ws = (char*)d_ws;
  double* qs = (double*)(ws + QS_OFF);
  double* ks = (double*)(ws + KS_OFF);
  int* counts = (int*)(ws + CNT_OFF);
  int* cols = (int*)(ws + COL_OFF);
  unsigned short* khm = (unsigned short*)(ws + KHM_OFF);
  unsigned short* vtm = (unsigned short*)(ws + VTM_OFF);
  double* probs = (double*)(ws + KHM_OFF);   // overlaid: dead before gather_kv writes khm
  float* outp = (float*)d_out;

  pool_kernel<<<dim3(60, 16, 2), 64, 0, stream>>>(qin, kin, qs, ks);
  scores_kernel<<<dim3(60, 16), 64, 0, stream>>>(qs, ks, probs);
  select_kernel<<<16, 256, 0, stream>>>(probs, counts, cols);
  gather_kv_kernel<<<dim3(60, 16), 256, 0, stream>>>(kin, vin, khm, vtm);
  attn_kernel<<<dim3(60, 16), 512, 0, stream>>>(qin, khm, vtm, counts, cols, outp);
}